// Round 4
// baseline (350.251 us; speedup 1.0000x reference)
//
#include <hip/hip_runtime.h>
#include <hip/hip_bf16.h>

// Problem constants (fixed by the reference)
#define I_CAPS 128
#define N_CAPS 5
#define D_CAPS 153
#define IN_DIM 768
#define NQ     256
#define CD     765      // N_CAPS * D_CAPS
#define HATLD  768      // padded leading dim of hat rows (cols 765..767 unused)
#define EPSF   1e-8f

typedef __hip_bfloat16 bf16;

__device__ __forceinline__ float wred(float x) {
#pragma unroll
  for (int off = 32; off; off >>= 1) x += __shfl_down(x, off, 64);
  return x;
}

// ---------------------------------------------------------------------------
// Kernel 0: input-dtype classifier. One wave reads 64 u32 words of m.
// bf16 inputs: low 16 bits of each word are a bf16 ~N(0,1) whose exponent
// bits[14:7] land in [118,134] (>99%). f32 inputs: bits[14:7] are mantissa
// bits (~uniform, ~7% hit). flag=1 -> bf16, flag=0 -> f32.
// Round-2/3 evidence: flag resolves to 0 (inputs are f32).
// ---------------------------------------------------------------------------
__global__ void classify_kernel(const unsigned* __restrict__ m_u32,
                                int* __restrict__ flag) {
  int lane = threadIdx.x & 63;
  unsigned u = m_u32[lane];
  int e = (u >> 7) & 0xFF;
  int hit = (e >= 118 && e <= 134) ? 1 : 0;
  unsigned long long mask = __ballot(hit);
  if (lane == 0) *flag = (__popcll(mask) >= 48) ? 1 : 0;
}

// ---------------------------------------------------------------------------
// Kernel 1: hat_all[row][0..764] = ([m;q] @ W + b), f32, row-padded to 768
// grid (12, 96), block (64, 4). Dual-dtype body via template.
// ---------------------------------------------------------------------------
template <bool ISB>
__device__ __forceinline__ float ld_in(const void* p, long idx) {
  if (ISB) return __bfloat162float(((const bf16*)p)[idx]);
  return ((const float*)p)[idx];
}

template <bool ISB>
__device__ void gemm_body(const void* m, const void* q, const void* W,
                          const void* b, float* hat) {
  __shared__ float As[4][IN_DIM];
  const int tx = threadIdx.x, ty = threadIdx.y;
  const int t = ty * 64 + tx;
  const int row0 = blockIdx.y * 4;

  for (int e = t; e < 4 * IN_DIM; e += 256) {
    int rr = row0 + e / IN_DIM;
    int k = e % IN_DIM;
    As[e / IN_DIM][k] = (rr < I_CAPS)
                            ? ld_in<ISB>(m, (long)rr * IN_DIM + k)
                            : ld_in<ISB>(q, (long)(rr - I_CAPS) * IN_DIM + k);
  }
  __syncthreads();

  const int col = blockIdx.x * 64 + tx;
  if (col >= CD) return;
  const int row = row0 + ty;

  float acc = 0.f;
#pragma unroll 8
  for (int k = 0; k < IN_DIM; ++k) {
    acc = fmaf(As[ty][k], ld_in<ISB>(W, (long)k * CD + col), acc);
  }
  hat[row * HATLD + col] = acc + ld_in<ISB>(b, col);
}

__global__ __launch_bounds__(256)
void gemm_kernel(const void* m, const void* q, const void* W, const void* b,
                 const int* __restrict__ flag, float* __restrict__ hat) {
  if (*flag)
    gemm_body<true>(m, q, W, b, hat);
  else
    gemm_body<false>(m, q, W, b, hat);
}

// ---------------------------------------------------------------------------
// Kernel 2: per-(i,c) stats of hat_m: mean and centered sum-of-squares
// (two-pass, matches reference). grid 3, block 256.
// ---------------------------------------------------------------------------
__global__ __launch_bounds__(256)
void stats_kernel(const float* __restrict__ hat,
                  float* __restrict__ mean_m, float* __restrict__ ssm) {
  int idx = blockIdx.x * 256 + threadIdx.x;
  if (idx >= I_CAPS * N_CAPS) return;
  int i = idx / N_CAPS, c = idx - i * N_CAPS;
  const float* hm = hat + i * HATLD + c * D_CAPS;
  float s = 0.f;
#pragma unroll 8
  for (int d = 0; d < D_CAPS; ++d) s += hm[d];
  float mu = s * (1.f / D_CAPS);
  float s2 = 0.f;
#pragma unroll 8
  for (int d = 0; d < D_CAPS; ++d) {
    float x = hm[d] - mu;
    s2 = fmaf(x, x, s2);
  }
  mean_m[idx] = mu;
  ssm[idx] = s2;
}

// ---------------------------------------------------------------------------
// Kernel 3: routing — one block per query. All per-query state in LDS.
// grid 256, block 256. Output dtype follows input dtype (flag).
// ---------------------------------------------------------------------------
__global__ __launch_bounds__(256)
void routing_kernel(const float* __restrict__ hat,
                    const float* __restrict__ mean_m,
                    const float* __restrict__ ssm,
                    const int* __restrict__ flag,
                    void* __restrict__ out_v) {
  __shared__ float tq[CD], vv[CD];
  __shared__ float aa[I_CAPS * N_CAPS], pp[I_CAPS * N_CAPS], dsp[I_CAPS * N_CAPS];
  __shared__ float meanq[N_CAPS], ssq[N_CAPS], sscale[N_CAPS];

  const int tid = threadIdx.x;
  const int qi = blockIdx.x;
  const int w = tid >> 6, lane = tid & 63;
  const float* hq = hat + (I_CAPS + qi) * HATLD;

  for (int cd = tid; cd < CD; cd += 256) tq[cd] = hq[cd];
  for (int idx = tid; idx < I_CAPS * N_CAPS; idx += 256) aa[idx] = 0.f;
  __syncthreads();

  // two-pass per-c stats of tq
  auto qstats = [&]() {
    for (int c = w; c < N_CAPS; c += 4) {
      float s = 0.f;
      for (int d = lane; d < D_CAPS; d += 64) s += tq[c * D_CAPS + d];
      s = wred(s);
      float mu = __shfl(s, 0, 64) * (1.f / D_CAPS);
      float s2 = 0.f;
      for (int d = lane; d < D_CAPS; d += 64) {
        float x = tq[c * D_CAPS + d] - mu;
        s2 = fmaf(x, x, s2);
      }
      s2 = wred(s2);
      if (lane == 0) {
        meanq[c] = mu;
        ssq[c] = s2;
      }
    }
  };

  // p = tanh(pearson(hat_m, tq)) — centered form
  auto compute_p = [&]() {
    for (int idx = tid; idx < I_CAPS * N_CAPS; idx += 256) {
      int i = idx / N_CAPS, c = idx - i * N_CAPS;
      const float* hm = hat + i * HATLD + c * D_CAPS;
      const float* tqc = tq + c * D_CAPS;
      float mum = mean_m[idx], muq = meanq[c];
      float dot = 0.f;
#pragma unroll 4
      for (int d = 0; d < D_CAPS; ++d)
        dot = fmaf(hm[d] - mum, tqc[d] - muq, dot);
      float den = sqrtf(ssm[idx]) * sqrtf(ssq[c]);
      pp[idx] = tanhf(dot / (den + EPSF));
    }
  };

  auto softmax_dsp = [&]() {
    if (tid < I_CAPS) {
      float av[N_CAPS], ev[N_CAPS];
      float mx = -1e30f;
#pragma unroll
      for (int c = 0; c < N_CAPS; ++c) {
        av[c] = aa[tid * N_CAPS + c];
        mx = fmaxf(mx, av[c]);
      }
      float s = 0.f;
#pragma unroll
      for (int c = 0; c < N_CAPS; ++c) {
        ev[c] = __expf(av[c] - mx);
        s += ev[c];
      }
      float inv = 1.f / s;
#pragma unroll
      for (int c = 0; c < N_CAPS; ++c)
        dsp[tid * N_CAPS + c] = ev[c] * inv + pp[tid * N_CAPS + c];
    }
  };

  auto hat_v = [&]() {
    for (int cd = tid; cd < CD; cd += 256) {
      int c = cd / D_CAPS;
      const float* col = hat + cd;  // cd == c*153+d; row i at offset i*HATLD
      float s = 0.f;
#pragma unroll 4
      for (int i = 0; i < I_CAPS; ++i)
        s = fmaf(dsp[i * N_CAPS + c], col[i * HATLD], s);
      vv[cd] = s;
    }
  };

  auto squash_scale = [&]() {
    for (int c = w; c < N_CAPS; c += 4) {
      float s2 = 0.f;
      for (int d = lane; d < D_CAPS; d += 64) {
        float x = vv[c * D_CAPS + d];
        s2 = fmaf(x, x, s2);
      }
      s2 = wred(s2);
      if (lane == 0) sscale[c] = (s2 / (1.f + s2)) * rsqrtf(s2 + EPSF);
    }
  };

  qstats();
  __syncthreads();
  compute_p();
  __syncthreads();

  for (int r = 0; r < 2; ++r) {
    softmax_dsp();
    __syncthreads();
    hat_v();
    __syncthreads();
    squash_scale();
    __syncthreads();
    for (int cd = tid; cd < CD; cd += 256) vv[cd] *= sscale[cd / D_CAPS];
    __syncthreads();
    for (int idx = tid; idx < I_CAPS * N_CAPS; idx += 256) {
      int i = idx / N_CAPS, c = idx - i * N_CAPS;
      const float* hm = hat + i * HATLD + c * D_CAPS;
      const float* vp = vv + c * D_CAPS;
      float dot = 0.f;
#pragma unroll 4
      for (int d = 0; d < D_CAPS; ++d) dot = fmaf(hm[d], vp[d], dot);
      aa[idx] += pp[idx] * dot;
    }
    for (int cd = tid; cd < CD; cd += 256) tq[cd] = 0.5f * (tq[cd] + vv[cd]);
    __syncthreads();
    qstats();
    __syncthreads();
    compute_p();
    __syncthreads();
  }

  softmax_dsp();
  __syncthreads();
  hat_v();
  __syncthreads();
  squash_scale();
  __syncthreads();

  // Output dtype follows the (classified) reference dtype:
  // flag==0 -> f32 (the reference is all-f32), flag==1 -> bf16.
  if (*flag == 0) {
    float* out = (float*)out_v;
    for (int cd = tid; cd < CD; cd += 256)
      out[qi * CD + cd] = vv[cd] * sscale[cd / D_CAPS];
  } else {
    bf16* out = (bf16*)out_v;
    for (int cd = tid; cd < CD; cd += 256)
      out[qi * CD + cd] = __float2bfloat16(vv[cd] * sscale[cd / D_CAPS]);
  }
}

// ---------------------------------------------------------------------------
extern "C" void kernel_launch(void* const* d_in, const int* in_sizes, int n_in,
                              void* d_out, int out_size, void* d_ws, size_t ws_size,
                              hipStream_t stream) {
  // Bind inputs by element count (dtype-independent, order-independent):
  // m=128*768=98304, q=256*768=196608, W=768*765=587520, b=765.
  const void *m = nullptr, *q = nullptr, *W = nullptr, *b = nullptr;
  for (int i = 0; i < n_in; ++i) {
    switch (in_sizes[i]) {
      case I_CAPS * IN_DIM: m = d_in[i]; break;   // 98304
      case NQ * IN_DIM:     q = d_in[i]; break;   // 196608
      case IN_DIM * CD:     W = d_in[i]; break;   // 587520
      case CD:              b = d_in[i]; break;   // 765
      default: break;
    }
  }
  if (!m || !q || !W || !b) {  // fallback: positional (dict order)
    m = d_in[0]; q = d_in[1]; W = d_in[2]; b = d_in[3];
  }

  // ws layout: small things first
  int*   flag   = (int*)d_ws;                  // 4 B (padded to 16 floats)
  float* mean_m = (float*)d_ws + 16;           // 640 f32
  float* ssm    = mean_m + 640;                // 640 f32
  float* hat    = ssm + 640;                   // 384 * 768 f32

  classify_kernel<<<1, 64, 0, stream>>>((const unsigned*)m, flag);
  gemm_kernel<<<dim3(12, 96), dim3(64, 4), 0, stream>>>(m, q, W, b, flag, hat);
  stats_kernel<<<3, 256, 0, stream>>>(hat, mean_m, ssm);
  routing_kernel<<<NQ, 256, 0, stream>>>(hat, mean_m, ssm, flag, d_out);
}

// Round 5
// 181.879 us; speedup vs baseline: 1.9257x; 1.9257x over previous
//
#include <hip/hip_runtime.h>
#include <hip/hip_bf16.h>

// Problem constants (fixed by the reference)
#define I_CAPS 128
#define N_CAPS 5
#define D_CAPS 153
#define IN_DIM 768
#define NQ     256
#define CD     765      // N_CAPS * D_CAPS
#define HATLD  768      // padded leading dim of hat rows (cols 765..767 unused)
#define NPAIR  640      // I_CAPS * N_CAPS
#define EPSF   1e-8f

typedef __hip_bfloat16 bf16;

__device__ __forceinline__ float wred(float x) {
#pragma unroll
  for (int off = 32; off; off >>= 1) x += __shfl_down(x, off, 64);
  return x;
}

// Stable fast tanh: sign(x) * (1 - e^{-2|x|}) / (1 + e^{-2|x|})
__device__ __forceinline__ float tanh_fast(float x) {
  float t = __expf(-2.f * fabsf(x));
  float r = (1.f - t) / (1.f + t);
  return copysignf(r, x);
}

// ---------------------------------------------------------------------------
// Kernel 0: input-dtype classifier (resolves to f32 on this harness; kept for
// robustness). flag=1 -> bf16 inputs, flag=0 -> f32 inputs.
// ---------------------------------------------------------------------------
__global__ void classify_kernel(const unsigned* __restrict__ m_u32,
                                int* __restrict__ flag) {
  int lane = threadIdx.x & 63;
  unsigned u = m_u32[lane];
  int e = (u >> 7) & 0xFF;
  int hit = (e >= 118 && e <= 134) ? 1 : 0;
  unsigned long long mask = __ballot(hit);
  if (lane == 0) *flag = (__popcll(mask) >= 48) ? 1 : 0;
}

// ---------------------------------------------------------------------------
// Kernel 1: hat_all[row][0..764] = ([m;q] @ W + b), f32, rows padded to 768
// grid (12, 96), block (64, 4). 8 k-partial accumulators break the serial
// FMA chain; A read from LDS as float4.
// ---------------------------------------------------------------------------
template <bool ISB>
__device__ __forceinline__ float ld_in(const void* p, long idx) {
  if (ISB) return __bfloat162float(((const bf16*)p)[idx]);
  return ((const float*)p)[idx];
}

template <bool ISB>
__device__ void gemm_body(const void* m, const void* q, const void* W,
                          const void* b, float* hat) {
  __shared__ float As[4][IN_DIM];
  const int tx = threadIdx.x, ty = threadIdx.y;
  const int t = ty * 64 + tx;
  const int row0 = blockIdx.y * 4;

  for (int e = t; e < 4 * IN_DIM; e += 256) {
    int rr = row0 + e / IN_DIM;
    int k = e % IN_DIM;
    As[e / IN_DIM][k] = (rr < I_CAPS)
                            ? ld_in<ISB>(m, (long)rr * IN_DIM + k)
                            : ld_in<ISB>(q, (long)(rr - I_CAPS) * IN_DIM + k);
  }
  __syncthreads();

  const int col = blockIdx.x * 64 + tx;
  if (col >= CD) return;
  const int row = row0 + ty;

  float a0 = 0.f, a1 = 0.f, a2 = 0.f, a3 = 0.f;
  float a4 = 0.f, a5 = 0.f, a6 = 0.f, a7 = 0.f;
  for (int k = 0; k < IN_DIM; k += 8) {
    const float4 A0 = *(const float4*)&As[ty][k];
    const float4 A1 = *(const float4*)&As[ty][k + 4];
    a0 = fmaf(A0.x, ld_in<ISB>(W, (long)(k + 0) * CD + col), a0);
    a1 = fmaf(A0.y, ld_in<ISB>(W, (long)(k + 1) * CD + col), a1);
    a2 = fmaf(A0.z, ld_in<ISB>(W, (long)(k + 2) * CD + col), a2);
    a3 = fmaf(A0.w, ld_in<ISB>(W, (long)(k + 3) * CD + col), a3);
    a4 = fmaf(A1.x, ld_in<ISB>(W, (long)(k + 4) * CD + col), a4);
    a5 = fmaf(A1.y, ld_in<ISB>(W, (long)(k + 5) * CD + col), a5);
    a6 = fmaf(A1.z, ld_in<ISB>(W, (long)(k + 6) * CD + col), a6);
    a7 = fmaf(A1.w, ld_in<ISB>(W, (long)(k + 7) * CD + col), a7);
  }
  float acc = ((a0 + a1) + (a2 + a3)) + ((a4 + a5) + (a6 + a7));
  hat[row * HATLD + col] = acc + ld_in<ISB>(b, col);
}

__global__ __launch_bounds__(256)
void gemm_kernel(const void* m, const void* q, const void* W, const void* b,
                 const int* __restrict__ flag, float* __restrict__ hat) {
  if (*flag)
    gemm_body<true>(m, q, W, b, hat);
  else
    gemm_body<false>(m, q, W, b, hat);
}

// ---------------------------------------------------------------------------
// Kernel 2: per-(i,c) stats of hat_m: mean + centered sum-of-squares.
// grid 3, block 256.
// ---------------------------------------------------------------------------
__global__ __launch_bounds__(256)
void stats_kernel(const float* __restrict__ hat,
                  float* __restrict__ mean_m, float* __restrict__ ssm) {
  int idx = blockIdx.x * 256 + threadIdx.x;
  if (idx >= NPAIR) return;
  int i = idx / N_CAPS, c = idx - i * N_CAPS;
  const float* hm = hat + i * HATLD + c * D_CAPS;
  float s = 0.f, s2 = 0.f;
#pragma unroll 8
  for (int d = 0; d < D_CAPS; ++d) {
    float x = hm[d];
    s += x;
    s2 = fmaf(x, x, s2);
  }
  float mu = s * (1.f / D_CAPS);
  mean_m[idx] = mu;
  ssm[idx] = fmaxf(s2 - (float)D_CAPS * mu * mu, 0.f);
}

// ---------------------------------------------------------------------------
// Kernel 3: routing — one block per query, 512 threads (8 waves).
// Dot products split 8 lanes/pair (coalesced, short chains, shfl reduce).
// grid 256, block 512.
// ---------------------------------------------------------------------------
__global__ __launch_bounds__(512)
void routing_kernel(const float* __restrict__ hat,
                    const float* __restrict__ mean_m,
                    const float* __restrict__ ssm,
                    const int* __restrict__ flag,
                    void* __restrict__ out_v) {
  __shared__ float tq[CD], vv[CD];
  __shared__ float aa[NPAIR], pp[NPAIR], dsp[NPAIR];
  __shared__ float meanq[N_CAPS], ssq[N_CAPS], sscale[N_CAPS];

  const int tid = threadIdx.x;
  const int qi = blockIdx.x;
  const int w = tid >> 6, lane = tid & 63;
  const int g = tid >> 3, sub = tid & 7;   // 64 groups of 8 lanes
  const float* hq = hat + (I_CAPS + qi) * HATLD;

  for (int cd = tid; cd < CD; cd += 512) tq[cd] = hq[cd];
  for (int idx = tid; idx < NPAIR; idx += 512) aa[idx] = 0.f;
  __syncthreads();

  // per-c stats of tq (waves 0..4, one c each)
  auto qstats = [&]() {
    if (w < N_CAPS) {
      const int c = w;
      float s = 0.f, s2 = 0.f;
      for (int d = lane; d < D_CAPS; d += 64) {
        float x = tq[c * D_CAPS + d];
        s += x;
        s2 = fmaf(x, x, s2);
      }
      s = wred(s);
      s2 = wred(s2);
      if (lane == 0) {
        float mu = s * (1.f / D_CAPS);
        meanq[c] = mu;
        ssq[c] = fmaxf(s2 - (float)D_CAPS * mu * mu, 0.f);
      }
    }
  };

  // p = tanh(pearson(hat_m_ic, tq_c)); 8 lanes per (i,c) pair
  auto compute_p = [&]() {
    for (int pair = g; pair < NPAIR; pair += 64) {
      int i = pair / N_CAPS, c = pair - i * N_CAPS;
      const float* hm = hat + i * HATLD + c * D_CAPS;
      const float* tqc = tq + c * D_CAPS;
      float acc = 0.f;
#pragma unroll
      for (int j = 0; j < 19; ++j) {
        int d = j * 8 + sub;
        acc = fmaf(hm[d], tqc[d], acc);
      }
      if (sub == 0) acc = fmaf(hm[152], tqc[152], acc);
      acc += __shfl_xor(acc, 1, 64);
      acc += __shfl_xor(acc, 2, 64);
      acc += __shfl_xor(acc, 4, 64);
      if (sub == 0) {
        float num = acc - (float)D_CAPS * mean_m[pair] * meanq[c];
        float den = sqrtf(ssm[pair]) * sqrtf(ssq[c]) + EPSF;
        pp[pair] = tanh_fast(num / den);
      }
    }
  };

  // a += p * (hat_m_ic . v_c); v = sscale[c] * vv_raw folded as scalar
  auto mdot_aa = [&]() {
    for (int pair = g; pair < NPAIR; pair += 64) {
      int i = pair / N_CAPS, c = pair - i * N_CAPS;
      const float* hm = hat + i * HATLD + c * D_CAPS;
      const float* vc = vv + c * D_CAPS;
      float acc = 0.f;
#pragma unroll
      for (int j = 0; j < 19; ++j) {
        int d = j * 8 + sub;
        acc = fmaf(hm[d], vc[d], acc);
      }
      if (sub == 0) acc = fmaf(hm[152], vc[152], acc);
      acc += __shfl_xor(acc, 1, 64);
      acc += __shfl_xor(acc, 2, 64);
      acc += __shfl_xor(acc, 4, 64);
      if (sub == 0) aa[pair] += pp[pair] * (sscale[c] * acc);
    }
  };

  // softmax(a)/BETA + p -> dsp (one thread per i)
  auto softmax_dsp = [&]() {
    if (tid < I_CAPS) {
      float av[N_CAPS], ev[N_CAPS];
      float mx = -1e30f;
#pragma unroll
      for (int c = 0; c < N_CAPS; ++c) {
        av[c] = aa[tid * N_CAPS + c];
        mx = fmaxf(mx, av[c]);
      }
      float s = 0.f;
#pragma unroll
      for (int c = 0; c < N_CAPS; ++c) {
        ev[c] = __expf(av[c] - mx);
        s += ev[c];
      }
      float inv = 1.f / s;
#pragma unroll
      for (int c = 0; c < N_CAPS; ++c)
        dsp[tid * N_CAPS + c] = ev[c] * inv + pp[tid * N_CAPS + c];
    }
  };

  // vv_raw[cd] = sum_i dsp[i,c] * hat_m[i,c,d]; 4-way i-unroll
  auto hat_v = [&]() {
    for (int cd = tid; cd < CD; cd += 512) {
      int c = cd / D_CAPS;
      const float* col = hat + cd;
      float a0 = 0.f, a1 = 0.f, a2 = 0.f, a3 = 0.f;
#pragma unroll 8
      for (int i = 0; i < I_CAPS; i += 4) {
        a0 = fmaf(dsp[(i + 0) * N_CAPS + c], col[(i + 0) * HATLD], a0);
        a1 = fmaf(dsp[(i + 1) * N_CAPS + c], col[(i + 1) * HATLD], a1);
        a2 = fmaf(dsp[(i + 2) * N_CAPS + c], col[(i + 2) * HATLD], a2);
        a3 = fmaf(dsp[(i + 3) * N_CAPS + c], col[(i + 3) * HATLD], a3);
      }
      vv[cd] = (a0 + a1) + (a2 + a3);
    }
  };

  // squash scale per c from raw vv
  auto squash_scale = [&]() {
    if (w < N_CAPS) {
      const int c = w;
      float s2 = 0.f;
      for (int d = lane; d < D_CAPS; d += 64) {
        float x = vv[c * D_CAPS + d];
        s2 = fmaf(x, x, s2);
      }
      s2 = wred(s2);
      if (lane == 0) sscale[c] = (s2 / (1.f + s2)) * rsqrtf(s2 + EPSF);
    }
  };

  qstats();
  __syncthreads();
  compute_p();
  __syncthreads();

  for (int r = 0; r < 2; ++r) {
    softmax_dsp();
    __syncthreads();
    hat_v();
    __syncthreads();
    squash_scale();
    __syncthreads();
    mdot_aa();
    // tq = 0.5*(tq + v);  v = vv_raw * sscale[c]
    for (int cd = tid; cd < CD; cd += 512)
      tq[cd] = 0.5f * (tq[cd] + vv[cd] * sscale[cd / D_CAPS]);
    __syncthreads();
    qstats();
    __syncthreads();
    compute_p();
    __syncthreads();
  }

  softmax_dsp();
  __syncthreads();
  hat_v();
  __syncthreads();
  squash_scale();
  __syncthreads();

  if (*flag == 0) {
    float* out = (float*)out_v;
    for (int cd = tid; cd < CD; cd += 512)
      out[qi * CD + cd] = vv[cd] * sscale[cd / D_CAPS];
  } else {
    bf16* out = (bf16*)out_v;
    for (int cd = tid; cd < CD; cd += 512)
      out[qi * CD + cd] = __float2bfloat16(vv[cd] * sscale[cd / D_CAPS]);
  }
}

// ---------------------------------------------------------------------------
extern "C" void kernel_launch(void* const* d_in, const int* in_sizes, int n_in,
                              void* d_out, int out_size, void* d_ws, size_t ws_size,
                              hipStream_t stream) {
  // Bind inputs by element count (order-independent):
  // m=98304, q=196608, W=587520, b=765.
  const void *m = nullptr, *q = nullptr, *W = nullptr, *b = nullptr;
  for (int i = 0; i < n_in; ++i) {
    switch (in_sizes[i]) {
      case I_CAPS * IN_DIM: m = d_in[i]; break;
      case NQ * IN_DIM:     q = d_in[i]; break;
      case IN_DIM * CD:     W = d_in[i]; break;
      case CD:              b = d_in[i]; break;
      default: break;
    }
  }
  if (!m || !q || !W || !b) {
    m = d_in[0]; q = d_in[1]; W = d_in[2]; b = d_in[3];
  }

  int*   flag   = (int*)d_ws;
  float* mean_m = (float*)d_ws + 16;
  float* ssm    = mean_m + 640;
  float* hat    = ssm + 640;     // 384 * 768 f32

  classify_kernel<<<1, 64, 0, stream>>>((const unsigned*)m, flag);
  gemm_kernel<<<dim3(12, 96), dim3(64, 4), 0, stream>>>(m, q, W, b, flag, hat);
  stats_kernel<<<3, 256, 0, stream>>>(hat, mean_m, ssm);
  routing_kernel<<<NQ, 512, 0, stream>>>(hat, mean_m, ssm, flag, d_out);
}